// Round 1
// baseline (226.684 us; speedup 1.0000x reference)
//
#include <hip/hip_runtime.h>
#include <hip/hip_fp16.h>

#define NN 50000
#define NE 800000
#define DD 128
#define NSTRIP 3125   // NN/16
#define NB 196        // dst>>8 buckets (49999>>8 == 195)
#define CHUNK 4096    // edges per shuf block; 196 chunks
#define MAXB 6144     // bucket capacity (mean 4096, sigma ~64)

// workspace layout, element (4-byte word) offsets
#define OF_LCNT  0            // int[256*196] per-bucket-per-block counts, bucket-major
#define OF_LOFS  50176        // int[256*196] per-block local offsets, bucket-major
#define OF_DINV  100352       // float[NN]
#define OF_DEG   150352       // int[NN] in-degree (excl. self-loop)
#define OF_OFFS2 200352       // int2[NN] per-node (start,end) into padded csr
#define OF_TMP2  300352       // uint[196*CHUNK] block-major slabs, bucket-grouped
#define OF_CSRW  1103168      // uint[196*MAXB] packed {src:16, w_fp16:16}
#define OF_H1    2307392      // ushort[NN*DD] bf16 h1 = x@W1 (unscaled)
#define OF_H2    5507392      // ushort[NN*DD] bf16 h2 (unscaled)
#define OF_W1H   8707392      // ushort[16384] fragment order
#define OF_W1L   8715584
#define OF_W2H   8723776
#define OF_W2L   8731968      // end 8740160 words = 35.0 MB

typedef __attribute__((ext_vector_type(8))) short bf8_t;   // 8 bf16 = 4 VGPRs
typedef __attribute__((ext_vector_type(8))) unsigned short us8;
typedef __attribute__((ext_vector_type(4))) float f32x4;

static __device__ __forceinline__ unsigned short f2bf(float f) {
    unsigned int u = __float_as_uint(f);
    unsigned int r = (u + 0x7fffu + ((u >> 16) & 1u)) >> 16;   // RNE
    return (unsigned short)r;
}
static __device__ __forceinline__ float bf2f(unsigned short h) {
    return __uint_as_float(((unsigned int)h) << 16);
}

// W1+W2 -> bf16 hi/lo split in B-fragment-contiguous order; also zeroes deg[].
__global__ void k_wconv(const float* __restrict__ W1, const float* __restrict__ W2,
                        ushort* __restrict__ w1h, ushort* __restrict__ w1l,
                        ushort* __restrict__ w2h, ushort* __restrict__ w2l,
                        int* __restrict__ deg) {
    int gg = blockIdx.x * 256 + threadIdx.x;
    for (int i = gg; i < NN; i += 4096) deg[i] = 0;   // zero deg for k_prep atomics
    const float* W = (gg < 2048) ? W1 : W2;
    ushort* wh = (gg < 2048) ? w1h : w2h;
    ushort* wl = (gg < 2048) ? w1l : w2l;
    int g = gg & 2047;
    int ntile = g >> 8;
    int kk = (g >> 6) & 3;
    int lane = g & 63;
    int k0 = kk * 32 + ((lane >> 4) * 8);
    int col = ntile * 16 + (lane & 15);
#pragma unroll
    for (int j = 0; j < 8; ++j) {
        float w = W[(k0 + j) * DD + col];
        unsigned short h = f2bf(w);
        wh[(size_t)g * 8 + j] = h;
        wl[(size_t)g * 8 + j] = f2bf(w - bf2f(h));
    }
}

// FUSED prep launch: blocks 0..195 = cursor-free edge shuffle (+ global deg
// histogram); blocks 196..977 = layer-1 MFMA GEMM (independent, co-scheduled).
__global__ __launch_bounds__(256) void k_prep(
        const int* __restrict__ src, const int* __restrict__ dst,
        int* __restrict__ lcnt_g, int* __restrict__ lofs_g,
        unsigned int* __restrict__ tmp2, int* __restrict__ deg,
        const float* __restrict__ X,
        const ushort* __restrict__ wh, const ushort* __restrict__ wl,
        ushort* __restrict__ H1) {
    __shared__ int lcnt[256];
    __shared__ int lsc[256];
    __shared__ int lcur[256];
    int tid = threadIdx.x;
    if (blockIdx.x < 196) {
        int blk = blockIdx.x;
        lcnt[tid] = 0;
        __syncthreads();
        int e0 = blk * CHUNK;
        int e1 = e0 + CHUNK; if (e1 > NE) e1 = NE;
        for (int e = e0 + tid; e < e1; e += 256) {
            int d = dst[e];
            atomicAdd(&lcnt[d >> 8], 1);
            atomicAdd(&deg[d], 1);          // global in-degree (for norm packing)
        }
        __syncthreads();
        int v = lcnt[tid];
        lsc[tid] = v;
        __syncthreads();
        for (int o = 1; o < 256; o <<= 1) {
            int t = (tid >= o) ? lsc[tid - o] : 0;
            __syncthreads();
            lsc[tid] += t;
            __syncthreads();
        }
        int excl = lsc[tid] - v;
        lcnt_g[tid * 196 + blk] = v;
        lofs_g[tid * 196 + blk] = excl;
        lcur[tid] = excl;
        __syncthreads();
        for (int e = e0 + tid; e < e1; e += 256) {
            int d = dst[e], s = src[e];
            int b = d >> 8;
            int r = atomicAdd(&lcur[b], 1);
            tmp2[blk * CHUNK + r] = ((unsigned int)s << 8) | (unsigned int)(d & 255);
        }
        return;
    }
    // ---- GEMM half ----
    int wave = tid >> 6;
    int lane = tid & 63;
    int strip = (blockIdx.x - 196) * 4 + wave;
    if (strip >= NSTRIP) return;
    int rb = strip << 4;
    int m = lane & 15;
    int quad = lane >> 4;
    const float* ar = X + (size_t)(rb + m) * DD;
    f32x4 acc[8];
#pragma unroll
    for (int t = 0; t < 8; ++t) acc[t] = (f32x4){0.f, 0.f, 0.f, 0.f};
#pragma unroll
    for (int kk = 0; kk < 4; ++kk) {
        float4 xa = *(const float4*)(ar + kk * 32 + quad * 8);
        float4 xb = *(const float4*)(ar + kk * 32 + quad * 8 + 4);
        float xs[8] = {xa.x, xa.y, xa.z, xa.w, xb.x, xb.y, xb.z, xb.w};
        bf8_t ah, al;
#pragma unroll
        for (int j = 0; j < 8; ++j) {
            unsigned short hh = f2bf(xs[j]);
            ah[j] = (short)hh;
            al[j] = (short)f2bf(xs[j] - bf2f(hh));
        }
#pragma unroll
        for (int t = 0; t < 8; ++t) {
            size_t bo = ((size_t)(t * 4 + kk) * 64 + lane) * 8;
            bf8_t bh = *(const bf8_t*)(wh + bo);
            bf8_t bl = *(const bf8_t*)(wl + bo);
            acc[t] = __builtin_amdgcn_mfma_f32_16x16x32_bf16(ah, bh, acc[t], 0, 0, 0);
            acc[t] = __builtin_amdgcn_mfma_f32_16x16x32_bf16(ah, bl, acc[t], 0, 0, 0);
            acc[t] = __builtin_amdgcn_mfma_f32_16x16x32_bf16(al, bh, acc[t], 0, 0, 0);
        }
    }
    // C/D layout (m89-verified): col = lane&15, row = quad*4 + reg
#pragma unroll
    for (int t = 0; t < 8; ++t) {
#pragma unroll
        for (int r = 0; r < 4; ++r)
            H1[(size_t)(rb + quad * 4 + r) * DD + t * 16 + m] = f2bf(acc[t][r]);
    }
}

// per-bucket gather + LDS counting sort -> padded CSR slab of packed records
// {src:16, w=dinv[src]*dinv[dst] as fp16:16}, per-node (start,end), dinv.
__global__ __launch_bounds__(256) void k_sort(const int* __restrict__ lcnt_g,
                                              const int* __restrict__ lofs_g,
                                              const unsigned int* __restrict__ tmp2,
                                              const int* __restrict__ deg,
                                              unsigned int* __restrict__ csrw,
                                              int2* __restrict__ offs2,
                                              float* __restrict__ dinv) {
    __shared__ unsigned int ent[MAXB];
    __shared__ int c[256];
    __shared__ int p[256];
    __shared__ int o[256];
    __shared__ int cnt[256];
    __shared__ int boff[256];
    __shared__ int cur[256];
    __shared__ float sdv[256];   // dinv of this bucket's nodes
    int b = blockIdx.x, tid = threadIdx.x;
    int cv = (tid < 196) ? lcnt_g[b * 196 + tid] : 0;
    o[tid] = (tid < 196) ? lofs_g[b * 196 + tid] : 0;
    c[tid] = cv;
    p[tid] = cv;
    cnt[tid] = 0;
    __syncthreads();
    for (int s = 1; s < 256; s <<= 1) {
        int t = (tid >= s) ? p[tid - s] : 0;
        __syncthreads();
        p[tid] += t;
        __syncthreads();
    }
    int nb = p[255];
    for (int i = tid; i < nb; i += 256) {
        int lo = 0, hi = 255;
#pragma unroll
        for (int it = 0; it < 8; ++it) {
            int mid = (lo + hi) >> 1;
            if (p[mid] > i) hi = mid; else lo = mid + 1;
        }
        int blk = lo;
        int j = i - (p[blk] - c[blk]);
        unsigned int e = tmp2[blk * CHUNK + o[blk] + j];
        ent[i] = e;
        atomicAdd(&cnt[e & 255], 1);
    }
    __syncthreads();
    int v = cnt[tid];
    boff[tid] = v;
    __syncthreads();
    for (int s = 1; s < 256; s <<= 1) {
        int t = (tid >= s) ? boff[tid - s] : 0;
        __syncthreads();
        boff[tid] += t;
        __syncthreads();
    }
    int excl = boff[tid] - v;
    int base = b * MAXB;
    int node = b * 256 + tid;
    float dv = rsqrtf((float)(v + 1));   // +1 self-loop
    sdv[tid] = dv;
    if (node < NN) {
        offs2[node] = make_int2(base + excl, base + excl + v);
        dinv[node] = dv;
    }
    cur[tid] = excl;
    __syncthreads();
    for (int i = tid; i < nb; i += 256) {
        unsigned int e = ent[i];
        int bin = e & 255;
        int s = (int)(e >> 8);
        int r = atomicAdd(&cur[bin], 1);
        float w = rsqrtf((float)(deg[s] + 1)) * sdv[bin];
        csrw[base + r] = ((unsigned int)s << 16) |
                         (unsigned int)__half_as_ushort(__float2half(w));
    }
}

// FUSED layer-1 aggregation + layer-2 GEMM.  512 threads, one block = 16
// nodes.  Phase 1: 8 waves x 2 nodes; 32-edge rounds (8 edges/quad, masked
// tail -> exactly ONE memory round for ~all nodes); records carry the
// pre-folded norm so the chain is record->row (2 hops, no dinv gather).
__global__ __launch_bounds__(512) void k_aggmm(const ushort* __restrict__ h1,
                                               const float* __restrict__ dinv,
                                               const int2* __restrict__ offs2,
                                               const unsigned int* __restrict__ csrw,
                                               const float* __restrict__ b1,
                                               const ushort* __restrict__ w2h,
                                               const ushort* __restrict__ w2l,
                                               ushort* __restrict__ h2) {
    __shared__ float xs[16][136];
    int wave = threadIdx.x >> 6;
    int lane = threadIdx.x & 63;
    int rb = blockIdx.x * 16;
    int q = lane >> 4;
    int l = lane & 15;
    const float* bp = b1 + 8 * l;
    // ---- phase 1: 2 nodes per wave ----
    for (int nn = 0; nn < 2; ++nn) {
        int node = rb + wave * 2 + nn;
        int2 oe = offs2[node];
        int e1 = oe.y;
        float a[8] = {0.f, 0.f, 0.f, 0.f, 0.f, 0.f, 0.f, 0.f};
        for (int eb = oe.x; eb < e1; eb += 32) {
            int s[8]; float w[8];
#pragma unroll
            for (int j = 0; j < 8; ++j) {
                int e = eb + q + 4 * j;
                int er = (e < e1) ? e : (e1 - 1);
                er = (er < 0) ? 0 : er;
                unsigned int rw = csrw[er];
                s[j] = (int)(rw >> 16);
                w[j] = (e < e1)
                     ? __half2float(__ushort_as_half((unsigned short)(rw & 0xffffu)))
                     : 0.f;
            }
            us8 v[8];
#pragma unroll
            for (int j = 0; j < 8; ++j)
                v[j] = *(const us8*)(h1 + ((size_t)s[j] << 7) + 8 * l);
#pragma unroll
            for (int j = 0; j < 8; ++j) {
#pragma unroll
                for (int d = 0; d < 8; ++d) a[d] += w[j] * bf2f(v[j][d]);
            }
        }
        float dnode = dinv[node];
        if (q == 0) {  // self-loop, weight dinv_d^2, counted once
            us8 v = *(const us8*)(h1 + ((size_t)node << 7) + 8 * l);
            float ws = dnode * dnode;
#pragma unroll
            for (int j = 0; j < 8; ++j) a[j] += ws * bf2f(v[j]);
        }
#pragma unroll
        for (int j = 0; j < 8; ++j) {
            a[j] += __shfl_xor(a[j], 16, 64);
            a[j] += __shfl_xor(a[j], 32, 64);
        }
        if (q == 0) {
            float* xr = &xs[wave * 2 + nn][8 * l];
#pragma unroll
            for (int j = 0; j < 8; ++j)
                xr[j] = fmaxf(a[j] + bp[j], 0.f);   // norm already folded in w
        }
    }
    __syncthreads();
    // ---- phase 2: each wave does N-tile t = wave ----
    int m = lane & 15;
    int quad = lane >> 4;
    int t = wave;
    f32x4 acc = (f32x4){0.f, 0.f, 0.f, 0.f};
#pragma unroll
    for (int kk = 0; kk < 4; ++kk) {
        const float* xr = &xs[m][kk * 32 + quad * 8];
        float4 xa = *(const float4*)xr;
        float4 xb = *(const float4*)(xr + 4);
        float xv[8] = {xa.x, xa.y, xa.z, xa.w, xb.x, xb.y, xb.z, xb.w};
        bf8_t ah, al;
#pragma unroll
        for (int j = 0; j < 8; ++j) {
            unsigned short hh = f2bf(xv[j]);
            ah[j] = (short)hh;
            al[j] = (short)f2bf(xv[j] - bf2f(hh));
        }
        size_t bo = ((size_t)(t * 4 + kk) * 64 + lane) * 8;
        bf8_t bh = *(const bf8_t*)(w2h + bo);
        bf8_t bl = *(const bf8_t*)(w2l + bo);
        acc = __builtin_amdgcn_mfma_f32_16x16x32_bf16(ah, bh, acc, 0, 0, 0);
        acc = __builtin_amdgcn_mfma_f32_16x16x32_bf16(ah, bl, acc, 0, 0, 0);
        acc = __builtin_amdgcn_mfma_f32_16x16x32_bf16(al, bh, acc, 0, 0, 0);
    }
#pragma unroll
    for (int r = 0; r < 4; ++r)
        h2[(size_t)(rb + quad * 4 + r) * DD + t * 16 + m] = f2bf(acc[r]);
}

// final aggregation: out[i] = relu( sum_e w_e*h2_s + dinv_i^2*h2_i + b2 )
__global__ __launch_bounds__(256) void k_agg(const ushort* __restrict__ h,
                                             const float* __restrict__ dinv,
                                             const int2* __restrict__ offs2,
                                             const unsigned int* __restrict__ csrw,
                                             const float* __restrict__ bias,
                                             float* __restrict__ outf) {
    int wave = threadIdx.x >> 6;
    int lane = threadIdx.x & 63;
    int node = blockIdx.x * 4 + wave;   // grid = NN/4 exactly
    int q = lane >> 4;
    int l = lane & 15;
    int2 oe = offs2[node];
    int e1 = oe.y;
    float a[8] = {0.f, 0.f, 0.f, 0.f, 0.f, 0.f, 0.f, 0.f};
    for (int eb = oe.x; eb < e1; eb += 32) {
        int s[8]; float w[8];
#pragma unroll
        for (int j = 0; j < 8; ++j) {
            int e = eb + q + 4 * j;
            int er = (e < e1) ? e : (e1 - 1);
            er = (er < 0) ? 0 : er;
            unsigned int rw = csrw[er];
            s[j] = (int)(rw >> 16);
            w[j] = (e < e1)
                 ? __half2float(__ushort_as_half((unsigned short)(rw & 0xffffu)))
                 : 0.f;
        }
        us8 v[8];
#pragma unroll
        for (int j = 0; j < 8; ++j)
            v[j] = *(const us8*)(h + ((size_t)s[j] << 7) + 8 * l);
#pragma unroll
        for (int j = 0; j < 8; ++j) {
#pragma unroll
            for (int d = 0; d < 8; ++d) a[d] += w[j] * bf2f(v[j][d]);
        }
    }
    float dnode = dinv[node];
    if (q == 0) {  // self-loop
        us8 v = *(const us8*)(h + ((size_t)node << 7) + 8 * l);
        float ws = dnode * dnode;
#pragma unroll
        for (int j = 0; j < 8; ++j) a[j] += ws * bf2f(v[j]);
    }
#pragma unroll
    for (int j = 0; j < 8; ++j) {
        a[j] += __shfl_xor(a[j], 16, 64);
        a[j] += __shfl_xor(a[j], 32, 64);
    }
    if (q == 0) {
        float* op = outf + (size_t)node * DD + 8 * l;
        const float* bp = bias + 8 * l;
        float4 o0, o1;
        o0.x = fmaxf(a[0] + bp[0], 0.f);
        o0.y = fmaxf(a[1] + bp[1], 0.f);
        o0.z = fmaxf(a[2] + bp[2], 0.f);
        o0.w = fmaxf(a[3] + bp[3], 0.f);
        o1.x = fmaxf(a[4] + bp[4], 0.f);
        o1.y = fmaxf(a[5] + bp[5], 0.f);
        o1.z = fmaxf(a[6] + bp[6], 0.f);
        o1.w = fmaxf(a[7] + bp[7], 0.f);
        *(float4*)op = o0;
        *(float4*)(op + 4) = o1;
    }
}

extern "C" void kernel_launch(void* const* d_in, const int* in_sizes, int n_in,
                              void* d_out, int out_size, void* d_ws, size_t ws_size,
                              hipStream_t stream) {
    const float* x  = (const float*)d_in[0];
    const int*   ei = (const int*)d_in[1];
    const float* W1 = (const float*)d_in[2];
    const float* b1 = (const float*)d_in[3];
    const float* W2 = (const float*)d_in[4];
    const float* b2 = (const float*)d_in[5];
    float* out = (float*)d_out;

    const int* src = ei;        // edge_index[0]
    const int* dst = ei + NE;   // edge_index[1]

    int*          wsi  = (int*)d_ws;
    float*        wsf  = (float*)d_ws;
    ushort*       wsu  = (ushort*)d_ws;
    unsigned int* wsuw = (unsigned int*)d_ws;
    int*    lcnt_g = wsi + OF_LCNT;
    int*    lofs_g = wsi + OF_LOFS;
    float*  dinv   = wsf + OF_DINV;
    int*    deg    = wsi + OF_DEG;
    int2*   offs2  = (int2*)(wsi + OF_OFFS2);
    unsigned int* tmp2 = wsuw + OF_TMP2;
    unsigned int* csrw = wsuw + OF_CSRW;
    ushort* h1     = wsu + (size_t)OF_H1 * 2;
    ushort* h2     = wsu + (size_t)OF_H2 * 2;
    ushort* w1h    = wsu + (size_t)OF_W1H * 2;
    ushort* w1l    = wsu + (size_t)OF_W1L * 2;
    ushort* w2h    = wsu + (size_t)OF_W2H * 2;
    ushort* w2l    = wsu + (size_t)OF_W2L * 2;

    // 1: W split tables + deg zero
    hipLaunchKernelGGL(k_wconv, dim3(16), dim3(256), 0, stream,
                       W1, W2, w1h, w1l, w2h, w2l, deg);
    // 2: edge shuffle + deg histogram (196 blocks) || layer-1 GEMM (782 blocks)
    hipLaunchKernelGGL(k_prep, dim3(196 + (NSTRIP + 3) / 4), dim3(256), 0, stream,
                       src, dst, lcnt_g, lofs_g, tmp2, deg, x, w1h, w1l, h1);
    // 3: per-bucket sort -> packed CSR {src,w} + offs2 + dinv
    hipLaunchKernelGGL(k_sort, dim3(NB), dim3(256), 0, stream,
                       lcnt_g, lofs_g, tmp2, deg, csrw, offs2, dinv);
    // 4: fused agg(L1)+relu+b1 -> @W2 -> h2
    hipLaunchKernelGGL(k_aggmm, dim3(NSTRIP), dim3(512), 0, stream,
                       h1, dinv, offs2, csrw, b1, w2h, w2l, h2);
    // 5: final aggregation -> out
    hipLaunchKernelGGL(k_agg, dim3(NN / 4), dim3(256), 0, stream,
                       h2, dinv, offs2, csrw, b2, out);
}

// Round 3
// 220.306 us; speedup vs baseline: 1.0290x; 1.0290x over previous
//
#include <hip/hip_runtime.h>

#define NN 50000
#define NE 800000
#define DD 128
#define NSTRIP 3125   // NN/16
#define NB 196        // dst>>8 buckets (49999>>8 == 195)
#define CHUNK 4096    // edges per shuf block; 196 chunks
#define MAXB 6144     // bucket capacity (mean 4096, sigma ~64)

// workspace layout, element (4-byte word) offsets
#define OF_LCNT  0            // int[256*196] per-bucket-per-block counts, bucket-major
#define OF_LOFS  50176        // int[256*196] per-block local offsets, bucket-major
#define OF_DINV  100352       // float[NN]
#define OF_OFFS2 150352       // int2[NN] per-node (start,end) into padded csru
#define OF_TMP2  250352       // uint[196*CHUNK] block-major slabs, bucket-grouped
#define OF_CSRU  1053168      // ushort[196*MAXB] padded sorted src
#define OF_H1    1655280      // ushort[NN*DD] bf16 h1 = x@W1 (unscaled)
#define OF_H2    4855280      // ushort[NN*DD] bf16 h2 (unscaled)
#define OF_W1H   8055280      // ushort[16384] fragment order
#define OF_W1L   8063472
#define OF_W2H   8071664
#define OF_W2L   8079856      // end 8088048 words = 32.4 MB

typedef __attribute__((ext_vector_type(8))) short bf8_t;   // 8 bf16 = 4 VGPRs
typedef __attribute__((ext_vector_type(8))) unsigned short us8;
typedef __attribute__((ext_vector_type(4))) float f32x4;

static __device__ __forceinline__ unsigned short f2bf(float f) {
    unsigned int u = __float_as_uint(f);
    unsigned int r = (u + 0x7fffu + ((u >> 16) & 1u)) >> 16;   // RNE
    return (unsigned short)r;
}
static __device__ __forceinline__ float bf2f(unsigned short h) {
    return __uint_as_float(((unsigned int)h) << 16);
}

// L1: blocks 0..15 = W split tables; blocks 16..211 = cursor-free edge
// shuffle.  Independent work, co-scheduled; no global state needed up front.
__global__ __launch_bounds__(256) void k_ws(
        const float* __restrict__ W1, const float* __restrict__ W2,
        ushort* __restrict__ w1h, ushort* __restrict__ w1l,
        ushort* __restrict__ w2h, ushort* __restrict__ w2l,
        const int* __restrict__ src, const int* __restrict__ dst,
        int* __restrict__ lcnt_g, int* __restrict__ lofs_g,
        unsigned int* __restrict__ tmp2) {
    __shared__ int lcnt[256];
    __shared__ int lsc[256];
    __shared__ int lcur[256];
    int tid = threadIdx.x;
    if (blockIdx.x < 16) {
        // ---- weight conversion ----
        int gg = blockIdx.x * 256 + tid;
        const float* W = (gg < 2048) ? W1 : W2;
        ushort* wh = (gg < 2048) ? w1h : w2h;
        ushort* wl = (gg < 2048) ? w1l : w2l;
        int g = gg & 2047;
        int ntile = g >> 8;
        int kk = (g >> 6) & 3;
        int lane = g & 63;
        int k0 = kk * 32 + ((lane >> 4) * 8);
        int col = ntile * 16 + (lane & 15);
#pragma unroll
        for (int j = 0; j < 8; ++j) {
            float w = W[(k0 + j) * DD + col];
            unsigned short h = f2bf(w);
            wh[(size_t)g * 8 + j] = h;
            wl[(size_t)g * 8 + j] = f2bf(w - bf2f(h));
        }
        return;
    }
    // ---- edge shuffle ----
    int blk = blockIdx.x - 16;
    lcnt[tid] = 0;
    __syncthreads();
    int e0 = blk * CHUNK;
    int e1 = e0 + CHUNK; if (e1 > NE) e1 = NE;
    for (int e = e0 + tid; e < e1; e += 256)
        atomicAdd(&lcnt[dst[e] >> 8], 1);
    __syncthreads();
    int v = lcnt[tid];
    lsc[tid] = v;
    __syncthreads();
    for (int o = 1; o < 256; o <<= 1) {
        int t = (tid >= o) ? lsc[tid - o] : 0;
        __syncthreads();
        lsc[tid] += t;
        __syncthreads();
    }
    int excl = lsc[tid] - v;
    lcnt_g[tid * 196 + blk] = v;
    lofs_g[tid * 196 + blk] = excl;
    lcur[tid] = excl;
    __syncthreads();
    for (int e = e0 + tid; e < e1; e += 256) {
        int d = dst[e], s = src[e];
        int b = d >> 8;
        int r = atomicAdd(&lcur[b], 1);
        tmp2[blk * CHUNK + r] = ((unsigned int)s << 8) | (unsigned int)(d & 255);
    }
}

// L2: blocks 0..195 = per-bucket counting sort -> padded CSR (16-bit src) +
// offs2 + dinv;  blocks 196..977 = layer-1 MFMA GEMM (1 strip/wave).
// Sort latency hides under GEMM occupancy; both halves are pass-verified
// bodies from earlier rounds.
__global__ __launch_bounds__(256) void k_sg(
        const int* __restrict__ lcnt_g, const int* __restrict__ lofs_g,
        const unsigned int* __restrict__ tmp2,
        ushort* __restrict__ csru, int2* __restrict__ offs2,
        float* __restrict__ dinv,
        const float* __restrict__ X,
        const ushort* __restrict__ wh, const ushort* __restrict__ wl,
        ushort* __restrict__ H1) {
    __shared__ unsigned int ent[MAXB];
    __shared__ int c[256];
    __shared__ int p[256];
    __shared__ int o[256];
    __shared__ int cnt[256];
    __shared__ int boff[256];
    __shared__ int cur[256];
    int tid = threadIdx.x;
    if (blockIdx.x < 196) {
        int b = blockIdx.x;
        int cv = (tid < 196) ? lcnt_g[b * 196 + tid] : 0;
        o[tid] = (tid < 196) ? lofs_g[b * 196 + tid] : 0;
        c[tid] = cv;
        p[tid] = cv;
        cnt[tid] = 0;
        __syncthreads();
        for (int s = 1; s < 256; s <<= 1) {
            int t = (tid >= s) ? p[tid - s] : 0;
            __syncthreads();
            p[tid] += t;
            __syncthreads();
        }
        int nb = p[255];
        for (int i = tid; i < nb; i += 256) {
            int lo = 0, hi = 255;
#pragma unroll
            for (int it = 0; it < 8; ++it) {
                int mid = (lo + hi) >> 1;
                if (p[mid] > i) hi = mid; else lo = mid + 1;
            }
            int blk = lo;
            int j = i - (p[blk] - c[blk]);
            unsigned int e = tmp2[blk * CHUNK + o[blk] + j];
            ent[i] = e;
            atomicAdd(&cnt[e & 255], 1);
        }
        __syncthreads();
        int v = cnt[tid];
        boff[tid] = v;
        __syncthreads();
        for (int s = 1; s < 256; s <<= 1) {
            int t = (tid >= s) ? boff[tid - s] : 0;
            __syncthreads();
            boff[tid] += t;
            __syncthreads();
        }
        int excl = boff[tid] - v;
        int base = b * MAXB;
        int node = b * 256 + tid;
        if (node < NN) {
            offs2[node] = make_int2(base + excl, base + excl + v);
            dinv[node] = rsqrtf((float)(v + 1));   // +1 self-loop
        }
        cur[tid] = excl;
        __syncthreads();
        for (int i = tid; i < nb; i += 256) {
            unsigned int e = ent[i];
            int bin = e & 255;
            int r = atomicAdd(&cur[bin], 1);
            csru[base + r] = (ushort)(e >> 8);
        }
        return;
    }
    // ---- GEMM half ----
    int wave = tid >> 6;
    int lane = tid & 63;
    int strip = (blockIdx.x - 196) * 4 + wave;
    if (strip >= NSTRIP) return;
    int rb = strip << 4;
    int m = lane & 15;
    int quad = lane >> 4;
    const float* ar = X + (size_t)(rb + m) * DD;
    f32x4 acc[8];
#pragma unroll
    for (int t = 0; t < 8; ++t) acc[t] = (f32x4){0.f, 0.f, 0.f, 0.f};
#pragma unroll
    for (int kk = 0; kk < 4; ++kk) {
        float4 xa = *(const float4*)(ar + kk * 32 + quad * 8);
        float4 xb = *(const float4*)(ar + kk * 32 + quad * 8 + 4);
        float xs[8] = {xa.x, xa.y, xa.z, xa.w, xb.x, xb.y, xb.z, xb.w};
        bf8_t ah, al;
#pragma unroll
        for (int j = 0; j < 8; ++j) {
            unsigned short hh = f2bf(xs[j]);
            ah[j] = (short)hh;
            al[j] = (short)f2bf(xs[j] - bf2f(hh));
        }
#pragma unroll
        for (int t = 0; t < 8; ++t) {
            size_t bo = ((size_t)(t * 4 + kk) * 64 + lane) * 8;
            bf8_t bh = *(const bf8_t*)(wh + bo);
            bf8_t bl = *(const bf8_t*)(wl + bo);
            acc[t] = __builtin_amdgcn_mfma_f32_16x16x32_bf16(ah, bh, acc[t], 0, 0, 0);
            acc[t] = __builtin_amdgcn_mfma_f32_16x16x32_bf16(ah, bl, acc[t], 0, 0, 0);
            acc[t] = __builtin_amdgcn_mfma_f32_16x16x32_bf16(al, bh, acc[t], 0, 0, 0);
        }
    }
    // C/D layout (m89-verified): col = lane&15, row = quad*4 + reg
#pragma unroll
    for (int t = 0; t < 8; ++t) {
#pragma unroll
        for (int r = 0; r < 4; ++r)
            H1[(size_t)(rb + quad * 4 + r) * DD + t * 16 + m] = f2bf(acc[t][r]);
    }
}

// FUSED layer-1 aggregation + layer-2 GEMM.  512 threads, one block = 16
// nodes.  Phase 1: 8 waves x 2 nodes; 32-edge masked rounds (one memory
// round for ~all nodes); dinv[s] gathered alongside the row (independent
// loads, L2-resident table).
__global__ __launch_bounds__(512) void k_aggmm(const ushort* __restrict__ h1,
                                               const float* __restrict__ dinv,
                                               const int2* __restrict__ offs2,
                                               const ushort* __restrict__ csru,
                                               const float* __restrict__ b1,
                                               const ushort* __restrict__ w2h,
                                               const ushort* __restrict__ w2l,
                                               ushort* __restrict__ h2) {
    __shared__ float xs[16][136];
    int wave = threadIdx.x >> 6;
    int lane = threadIdx.x & 63;
    int rb = blockIdx.x * 16;
    int q = lane >> 4;
    int l = lane & 15;
    const float* bp = b1 + 8 * l;
    // ---- phase 1: 2 nodes per wave ----
    for (int nn = 0; nn < 2; ++nn) {
        int node = rb + wave * 2 + nn;
        int2 oe = offs2[node];
        int e1 = oe.y;
        float a[8] = {0.f, 0.f, 0.f, 0.f, 0.f, 0.f, 0.f, 0.f};
        for (int eb = oe.x; eb < e1; eb += 32) {
            int s[8]; float w[8];
#pragma unroll
            for (int j = 0; j < 8; ++j) {
                int e = eb + q + 4 * j;
                int er = (e < e1) ? e : (e1 - 1);
                er = (er < 0) ? 0 : er;
                s[j] = (int)csru[er];
                w[j] = (e < e1) ? dinv[s[j]] : 0.f;
            }
            us8 v[8];
#pragma unroll
            for (int j = 0; j < 8; ++j)
                v[j] = *(const us8*)(h1 + ((size_t)s[j] << 7) + 8 * l);
#pragma unroll
            for (int j = 0; j < 8; ++j) {
#pragma unroll
                for (int d = 0; d < 8; ++d) a[d] += w[j] * bf2f(v[j][d]);
            }
        }
        float dnode = dinv[node];
        if (q == 0) {  // self-loop term dinv_d*h1_d, counted once
            us8 v = *(const us8*)(h1 + ((size_t)node << 7) + 8 * l);
#pragma unroll
            for (int j = 0; j < 8; ++j) a[j] += dnode * bf2f(v[j]);
        }
#pragma unroll
        for (int j = 0; j < 8; ++j) {
            a[j] += __shfl_xor(a[j], 16, 64);
            a[j] += __shfl_xor(a[j], 32, 64);
        }
        if (q == 0) {
            float* xr = &xs[wave * 2 + nn][8 * l];
#pragma unroll
            for (int j = 0; j < 8; ++j)
                xr[j] = fmaxf(dnode * a[j] + bp[j], 0.f);
        }
    }
    __syncthreads();
    // ---- phase 2: each wave does N-tile t = wave ----
    int m = lane & 15;
    int quad = lane >> 4;
    int t = wave;
    f32x4 acc = (f32x4){0.f, 0.f, 0.f, 0.f};
#pragma unroll
    for (int kk = 0; kk < 4; ++kk) {
        const float* xr = &xs[m][kk * 32 + quad * 8];
        float4 xa = *(const float4*)xr;
        float4 xb = *(const float4*)(xr + 4);
        float xv[8] = {xa.x, xa.y, xa.z, xa.w, xb.x, xb.y, xb.z, xb.w};
        bf8_t ah, al;
#pragma unroll
        for (int j = 0; j < 8; ++j) {
            unsigned short hh = f2bf(xv[j]);
            ah[j] = (short)hh;
            al[j] = (short)f2bf(xv[j] - bf2f(hh));
        }
        size_t bo = ((size_t)(t * 4 + kk) * 64 + lane) * 8;
        bf8_t bh = *(const bf8_t*)(w2h + bo);
        bf8_t bl = *(const bf8_t*)(w2l + bo);
        acc = __builtin_amdgcn_mfma_f32_16x16x32_bf16(ah, bh, acc, 0, 0, 0);
        acc = __builtin_amdgcn_mfma_f32_16x16x32_bf16(ah, bl, acc, 0, 0, 0);
        acc = __builtin_amdgcn_mfma_f32_16x16x32_bf16(al, bh, acc, 0, 0, 0);
    }
#pragma unroll
    for (int r = 0; r < 4; ++r)
        h2[(size_t)(rb + quad * 4 + r) * DD + t * 16 + m] = f2bf(acc[r]);
}

// final aggregation: out[i] = relu( dinv_i*(sum dinv_s*h2_s + dinv_i*h2_i) + b2 )
__global__ __launch_bounds__(256) void k_agg(const ushort* __restrict__ h,
                                             const float* __restrict__ dinv,
                                             const int2* __restrict__ offs2,
                                             const ushort* __restrict__ csru,
                                             const float* __restrict__ bias,
                                             float* __restrict__ outf) {
    int wave = threadIdx.x >> 6;
    int lane = threadIdx.x & 63;
    int node = blockIdx.x * 4 + wave;   // grid = NN/4 exactly
    int q = lane >> 4;
    int l = lane & 15;
    int2 oe = offs2[node];
    int e1 = oe.y;
    float a[8] = {0.f, 0.f, 0.f, 0.f, 0.f, 0.f, 0.f, 0.f};
    for (int eb = oe.x; eb < e1; eb += 32) {
        int s[8]; float w[8];
#pragma unroll
        for (int j = 0; j < 8; ++j) {
            int e = eb + q + 4 * j;
            int er = (e < e1) ? e : (e1 - 1);
            er = (er < 0) ? 0 : er;
            s[j] = (int)csru[er];
            w[j] = (e < e1) ? dinv[s[j]] : 0.f;
        }
        us8 v[8];
#pragma unroll
        for (int j = 0; j < 8; ++j)
            v[j] = *(const us8*)(h + ((size_t)s[j] << 7) + 8 * l);
#pragma unroll
        for (int j = 0; j < 8; ++j) {
#pragma unroll
            for (int d = 0; d < 8; ++d) a[d] += w[j] * bf2f(v[j][d]);
        }
    }
    float dnode = dinv[node];
    if (q == 0) {  // self-loop
        us8 v = *(const us8*)(h + ((size_t)node << 7) + 8 * l);
#pragma unroll
        for (int j = 0; j < 8; ++j) a[j] += dnode * bf2f(v[j]);
    }
#pragma unroll
    for (int j = 0; j < 8; ++j) {
        a[j] += __shfl_xor(a[j], 16, 64);
        a[j] += __shfl_xor(a[j], 32, 64);
    }
    if (q == 0) {
        float* op = outf + (size_t)node * DD + 8 * l;
        const float* bp = bias + 8 * l;
        float4 o0, o1;
        o0.x = fmaxf(dnode * a[0] + bp[0], 0.f);
        o0.y = fmaxf(dnode * a[1] + bp[1], 0.f);
        o0.z = fmaxf(dnode * a[2] + bp[2], 0.f);
        o0.w = fmaxf(dnode * a[3] + bp[3], 0.f);
        o1.x = fmaxf(dnode * a[4] + bp[4], 0.f);
        o1.y = fmaxf(dnode * a[5] + bp[5], 0.f);
        o1.z = fmaxf(dnode * a[6] + bp[6], 0.f);
        o1.w = fmaxf(dnode * a[7] + bp[7], 0.f);
        *(float4*)op = o0;
        *(float4*)(op + 4) = o1;
    }
}

extern "C" void kernel_launch(void* const* d_in, const int* in_sizes, int n_in,
                              void* d_out, int out_size, void* d_ws, size_t ws_size,
                              hipStream_t stream) {
    const float* x  = (const float*)d_in[0];
    const int*   ei = (const int*)d_in[1];
    const float* W1 = (const float*)d_in[2];
    const float* b1 = (const float*)d_in[3];
    const float* W2 = (const float*)d_in[4];
    const float* b2 = (const float*)d_in[5];
    float* out = (float*)d_out;

    const int* src = ei;        // edge_index[0]
    const int* dst = ei + NE;   // edge_index[1]

    int*          wsi  = (int*)d_ws;
    float*        wsf  = (float*)d_ws;
    ushort*       wsu  = (ushort*)d_ws;
    unsigned int* wsuw = (unsigned int*)d_ws;
    int*    lcnt_g = wsi + OF_LCNT;
    int*    lofs_g = wsi + OF_LOFS;
    float*  dinv   = wsf + OF_DINV;
    int2*   offs2  = (int2*)(wsi + OF_OFFS2);
    unsigned int* tmp2 = wsuw + OF_TMP2;
    ushort* csru   = wsu + (size_t)OF_CSRU * 2;
    ushort* h1     = wsu + (size_t)OF_H1 * 2;
    ushort* h2     = wsu + (size_t)OF_H2 * 2;
    ushort* w1h    = wsu + (size_t)OF_W1H * 2;
    ushort* w1l    = wsu + (size_t)OF_W1L * 2;
    ushort* w2h    = wsu + (size_t)OF_W2H * 2;
    ushort* w2l    = wsu + (size_t)OF_W2L * 2;

    // 1: wconv (16 blk) || edge shuffle (196 blk)
    hipLaunchKernelGGL(k_ws, dim3(16 + 196), dim3(256), 0, stream,
                       W1, W2, w1h, w1l, w2h, w2l,
                       src, dst, lcnt_g, lofs_g, tmp2);
    // 2: sort (196 blk) || layer-1 GEMM (782 blk)
    hipLaunchKernelGGL(k_sg, dim3(196 + (NSTRIP + 3) / 4), dim3(256), 0, stream,
                       lcnt_g, lofs_g, tmp2, csru, offs2, dinv,
                       x, w1h, w1l, h1);
    // 3: fused agg(L1)+relu+b1 -> @W2 -> h2
    hipLaunchKernelGGL(k_aggmm, dim3(NSTRIP), dim3(512), 0, stream,
                       h1, dinv, offs2, csru, b1, w2h, w2l, h2);
    // 4: final aggregation -> out
    hipLaunchKernelGGL(k_agg, dim3(NN / 4), dim3(256), 0, stream,
                       h2, dinv, offs2, csru, b2, out);
}

// Round 4
// 217.269 us; speedup vs baseline: 1.0433x; 1.0140x over previous
//
#include <hip/hip_runtime.h>
#include <hip/hip_fp16.h>

#define NN 50000
#define NE 800000
#define DD 128
#define NSTRIP 3125   // NN/16
#define NB 196        // dst>>8 buckets (49999>>8 == 195)
#define CHUNK 4096    // edges per shuf block; 196 chunks
#define MAXB 6144     // bucket capacity (mean 4096, sigma ~64)
#define ZROW NN       // dedicated zero row index in h1/h2 (masked edge slots)

// workspace layout, element (4-byte word) offsets
#define OF_LCNT  0            // int[256*196] per-bucket-per-block counts, bucket-major
#define OF_LOFS  50176        // int[256*196] per-block local offsets, bucket-major
#define OF_DINV  100352       // float[NN]
#define OF_DEG   150352       // int[NN] in-degree (excl. self-loop)
#define OF_OFFS2 200352       // int2[NN] per-node (start,end) into padded csru
#define OF_TMP2  300352       // uint[196*CHUNK] block-major slabs, bucket-grouped
#define OF_CSRU  1103168      // ushort[196*MAXB] padded sorted src
#define OF_H1    1705280      // ushort[(NN+1)*DD] fp16 h1s = dinv*(x@W1)
#define OF_H2    4905344      // ushort[(NN+1)*DD] fp16 h2s = dinv*h2
#define OF_W1H   8105408      // ushort[16384] fragment order
#define OF_W1L   8113600
#define OF_W2H   8121792
#define OF_W2L   8129984      // end 8138176 words = 32.55 MB

typedef __attribute__((ext_vector_type(8))) short bf8_t;   // 8 bf16 = 4 VGPRs
typedef __attribute__((ext_vector_type(8))) unsigned short us8;
typedef __attribute__((ext_vector_type(4))) float f32x4;

static __device__ __forceinline__ unsigned short f2bf(float f) {
    unsigned int u = __float_as_uint(f);
    unsigned int r = (u + 0x7fffu + ((u >> 16) & 1u)) >> 16;   // RNE
    return (unsigned short)r;
}
static __device__ __forceinline__ float bf2f(unsigned short h) {
    return __uint_as_float(((unsigned int)h) << 16);
}
static __device__ __forceinline__ unsigned short f2h(float f) {
    return __half_as_ushort(__float2half(f));
}
static __device__ __forceinline__ float h2f(unsigned short u) {
    return __half2float(__ushort_as_half(u));
}

// L0: zero deg[] (atomic histogram target) + the ZROW rows of h1/h2.
__global__ __launch_bounds__(256) void k_zero(int* __restrict__ deg,
                                              ushort* __restrict__ h1,
                                              ushort* __restrict__ h2) {
    int g = blockIdx.x * 256 + threadIdx.x;
    if (g < NN) deg[g] = 0;
    if (g < 64) ((unsigned int*)(h1 + (size_t)ZROW * DD))[g] = 0u;
    else if (g < 128) ((unsigned int*)(h2 + (size_t)ZROW * DD))[g - 64] = 0u;
}

// L1: blocks 0..15 = W split tables; blocks 16..211 = cursor-free edge
// shuffle + global in-degree histogram (deg pre-zeroed by k_zero).
__global__ __launch_bounds__(256) void k_ws(
        const float* __restrict__ W1, const float* __restrict__ W2,
        ushort* __restrict__ w1h, ushort* __restrict__ w1l,
        ushort* __restrict__ w2h, ushort* __restrict__ w2l,
        const int* __restrict__ src, const int* __restrict__ dst,
        int* __restrict__ lcnt_g, int* __restrict__ lofs_g,
        unsigned int* __restrict__ tmp2, int* __restrict__ deg) {
    __shared__ int lcnt[256];
    __shared__ int lsc[256];
    __shared__ int lcur[256];
    int tid = threadIdx.x;
    if (blockIdx.x < 16) {
        // ---- weight conversion ----
        int gg = blockIdx.x * 256 + tid;
        const float* W = (gg < 2048) ? W1 : W2;
        ushort* wh = (gg < 2048) ? w1h : w2h;
        ushort* wl = (gg < 2048) ? w1l : w2l;
        int g = gg & 2047;
        int ntile = g >> 8;
        int kk = (g >> 6) & 3;
        int lane = g & 63;
        int k0 = kk * 32 + ((lane >> 4) * 8);
        int col = ntile * 16 + (lane & 15);
#pragma unroll
        for (int j = 0; j < 8; ++j) {
            float w = W[(k0 + j) * DD + col];
            unsigned short h = f2bf(w);
            wh[(size_t)g * 8 + j] = h;
            wl[(size_t)g * 8 + j] = f2bf(w - bf2f(h));
        }
        return;
    }
    // ---- edge shuffle ----
    int blk = blockIdx.x - 16;
    lcnt[tid] = 0;
    __syncthreads();
    int e0 = blk * CHUNK;
    int e1 = e0 + CHUNK; if (e1 > NE) e1 = NE;
    for (int e = e0 + tid; e < e1; e += 256) {
        int d = dst[e];
        atomicAdd(&lcnt[d >> 8], 1);
        atomicAdd(&deg[d], 1);          // global in-degree (round-1: ~free)
    }
    __syncthreads();
    int v = lcnt[tid];
    lsc[tid] = v;
    __syncthreads();
    for (int o = 1; o < 256; o <<= 1) {
        int t = (tid >= o) ? lsc[tid - o] : 0;
        __syncthreads();
        lsc[tid] += t;
        __syncthreads();
    }
    int excl = lsc[tid] - v;
    lcnt_g[tid * 196 + blk] = v;
    lofs_g[tid * 196 + blk] = excl;
    lcur[tid] = excl;
    __syncthreads();
    for (int e = e0 + tid; e < e1; e += 256) {
        int d = dst[e], s = src[e];
        int b = d >> 8;
        int r = atomicAdd(&lcur[b], 1);
        tmp2[blk * CHUNK + r] = ((unsigned int)s << 8) | (unsigned int)(d & 255);
    }
}

// L2: blocks 0..195 = per-bucket counting sort -> padded CSR (16-bit src) +
// offs2 + dinv;  blocks 196..977 = layer-1 MFMA GEMM writing h1s =
// dinv[row]*(x@W1) in fp16 (dinv recomputed from deg[] at C-write; deg is
// complete after L1, so no dependency on the co-running sort).
__global__ __launch_bounds__(256) void k_sg(
        const int* __restrict__ lcnt_g, const int* __restrict__ lofs_g,
        const unsigned int* __restrict__ tmp2, const int* __restrict__ deg,
        ushort* __restrict__ csru, int2* __restrict__ offs2,
        float* __restrict__ dinv,
        const float* __restrict__ X,
        const ushort* __restrict__ wh, const ushort* __restrict__ wl,
        ushort* __restrict__ H1) {
    __shared__ unsigned int ent[MAXB];
    __shared__ int c[256];
    __shared__ int p[256];
    __shared__ int o[256];
    __shared__ int cnt[256];
    __shared__ int boff[256];
    __shared__ int cur[256];
    int tid = threadIdx.x;
    if (blockIdx.x < 196) {
        int b = blockIdx.x;
        int cv = (tid < 196) ? lcnt_g[b * 196 + tid] : 0;
        o[tid] = (tid < 196) ? lofs_g[b * 196 + tid] : 0;
        c[tid] = cv;
        p[tid] = cv;
        cnt[tid] = 0;
        __syncthreads();
        for (int s = 1; s < 256; s <<= 1) {
            int t = (tid >= s) ? p[tid - s] : 0;
            __syncthreads();
            p[tid] += t;
            __syncthreads();
        }
        int nb = p[255];
        for (int i = tid; i < nb; i += 256) {
            int lo = 0, hi = 255;
#pragma unroll
            for (int it = 0; it < 8; ++it) {
                int mid = (lo + hi) >> 1;
                if (p[mid] > i) hi = mid; else lo = mid + 1;
            }
            int blk = lo;
            int j = i - (p[blk] - c[blk]);
            unsigned int e = tmp2[blk * CHUNK + o[blk] + j];
            ent[i] = e;
            atomicAdd(&cnt[e & 255], 1);
        }
        __syncthreads();
        int v = cnt[tid];
        boff[tid] = v;
        __syncthreads();
        for (int s = 1; s < 256; s <<= 1) {
            int t = (tid >= s) ? boff[tid - s] : 0;
            __syncthreads();
            boff[tid] += t;
            __syncthreads();
        }
        int excl = boff[tid] - v;
        int base = b * MAXB;
        int node = b * 256 + tid;
        if (node < NN) {
            offs2[node] = make_int2(base + excl, base + excl + v);
            dinv[node] = rsqrtf((float)(v + 1));   // +1 self-loop
        }
        cur[tid] = excl;
        __syncthreads();
        for (int i = tid; i < nb; i += 256) {
            unsigned int e = ent[i];
            int bin = e & 255;
            int r = atomicAdd(&cur[bin], 1);
            csru[base + r] = (ushort)(e >> 8);
        }
        return;
    }
    // ---- GEMM half ----
    int wave = tid >> 6;
    int lane = tid & 63;
    int strip = (blockIdx.x - 196) * 4 + wave;
    if (strip >= NSTRIP) return;
    int rb = strip << 4;
    int m = lane & 15;
    int quad = lane >> 4;
    const float* ar = X + (size_t)(rb + m) * DD;
    f32x4 acc[8];
#pragma unroll
    for (int t = 0; t < 8; ++t) acc[t] = (f32x4){0.f, 0.f, 0.f, 0.f};
#pragma unroll
    for (int kk = 0; kk < 4; ++kk) {
        float4 xa = *(const float4*)(ar + kk * 32 + quad * 8);
        float4 xb = *(const float4*)(ar + kk * 32 + quad * 8 + 4);
        float xs[8] = {xa.x, xa.y, xa.z, xa.w, xb.x, xb.y, xb.z, xb.w};
        bf8_t ah, al;
#pragma unroll
        for (int j = 0; j < 8; ++j) {
            unsigned short hh = f2bf(xs[j]);
            ah[j] = (short)hh;
            al[j] = (short)f2bf(xs[j] - bf2f(hh));
        }
#pragma unroll
        for (int t = 0; t < 8; ++t) {
            size_t bo = ((size_t)(t * 4 + kk) * 64 + lane) * 8;
            bf8_t bh = *(const bf8_t*)(wh + bo);
            bf8_t bl = *(const bf8_t*)(wl + bo);
            acc[t] = __builtin_amdgcn_mfma_f32_16x16x32_bf16(ah, bh, acc[t], 0, 0, 0);
            acc[t] = __builtin_amdgcn_mfma_f32_16x16x32_bf16(ah, bl, acc[t], 0, 0, 0);
            acc[t] = __builtin_amdgcn_mfma_f32_16x16x32_bf16(al, bh, acc[t], 0, 0, 0);
        }
    }
    // dinv for this thread's 4 output rows (deg complete after L1)
    int4 dg = *(const int4*)(deg + rb + quad * 4);
    float dvv[4] = {rsqrtf((float)(dg.x + 1)), rsqrtf((float)(dg.y + 1)),
                    rsqrtf((float)(dg.z + 1)), rsqrtf((float)(dg.w + 1))};
    // C/D layout (m89-verified): col = lane&15, row = quad*4 + reg
#pragma unroll
    for (int t = 0; t < 8; ++t) {
#pragma unroll
        for (int r = 0; r < 4; ++r)
            H1[(size_t)(rb + quad * 4 + r) * DD + t * 16 + m] =
                f2h(dvv[r] * acc[t][r]);
    }
}

// FUSED layer-1 aggregation + layer-2 GEMM.  512 threads, one block = 16
// nodes.  Phase 1: 8 waves x 2 nodes; 32-edge masked rounds over PRE-SCALED
// fp16 rows -> pure unweighted row-sum (no dinv gather, no per-edge fma
// weight; masked slots read the ZROW zero row).
__global__ __launch_bounds__(512) void k_aggmm(const ushort* __restrict__ h1,
                                               const float* __restrict__ dinv,
                                               const int2* __restrict__ offs2,
                                               const ushort* __restrict__ csru,
                                               const float* __restrict__ b1,
                                               const ushort* __restrict__ w2h,
                                               const ushort* __restrict__ w2l,
                                               ushort* __restrict__ h2) {
    __shared__ float xs[16][136];
    int wave = threadIdx.x >> 6;
    int lane = threadIdx.x & 63;
    int rb = blockIdx.x * 16;
    int q = lane >> 4;
    int l = lane & 15;
    const float* bp = b1 + 8 * l;
    // ---- phase 1: 2 nodes per wave ----
    for (int nn = 0; nn < 2; ++nn) {
        int node = rb + wave * 2 + nn;
        int2 oe = offs2[node];
        int e1 = oe.y;
        float a[8] = {0.f, 0.f, 0.f, 0.f, 0.f, 0.f, 0.f, 0.f};
        for (int eb = oe.x; eb < e1; eb += 32) {
            int s[8];
#pragma unroll
            for (int j = 0; j < 8; ++j) {
                int e = eb + q + 4 * j;
                int er = (e < e1) ? e : (e1 - 1);
                er = (er < 0) ? 0 : er;
                int sv = (int)csru[er];
                s[j] = (e < e1) ? sv : ZROW;
            }
            us8 v[8];
#pragma unroll
            for (int j = 0; j < 8; ++j)
                v[j] = *(const us8*)(h1 + ((size_t)s[j] << 7) + 8 * l);
#pragma unroll
            for (int j = 0; j < 8; ++j) {
#pragma unroll
                for (int d = 0; d < 8; ++d) a[d] += h2f(v[j][d]);
            }
        }
        if (q == 0) {  // self-loop: + h1s[node] (pre-scaled)
            us8 v = *(const us8*)(h1 + ((size_t)node << 7) + 8 * l);
#pragma unroll
            for (int j = 0; j < 8; ++j) a[j] += h2f(v[j]);
        }
#pragma unroll
        for (int j = 0; j < 8; ++j) {
            a[j] += __shfl_xor(a[j], 16, 64);
            a[j] += __shfl_xor(a[j], 32, 64);
        }
        if (q == 0) {
            float dnode = dinv[node];
            float* xr = &xs[wave * 2 + nn][8 * l];
#pragma unroll
            for (int j = 0; j < 8; ++j)
                xr[j] = fmaxf(dnode * a[j] + bp[j], 0.f);
        }
    }
    __syncthreads();
    // ---- phase 2: each wave does N-tile t = wave; h2 stored PRE-SCALED ----
    int m = lane & 15;
    int quad = lane >> 4;
    int t = wave;
    f32x4 acc = (f32x4){0.f, 0.f, 0.f, 0.f};
#pragma unroll
    for (int kk = 0; kk < 4; ++kk) {
        const float* xr = &xs[m][kk * 32 + quad * 8];
        float4 xa = *(const float4*)xr;
        float4 xb = *(const float4*)(xr + 4);
        float xv[8] = {xa.x, xa.y, xa.z, xa.w, xb.x, xb.y, xb.z, xb.w};
        bf8_t ah, al;
#pragma unroll
        for (int j = 0; j < 8; ++j) {
            unsigned short hh = f2bf(xv[j]);
            ah[j] = (short)hh;
            al[j] = (short)f2bf(xv[j] - bf2f(hh));
        }
        size_t bo = ((size_t)(t * 4 + kk) * 64 + lane) * 8;
        bf8_t bh = *(const bf8_t*)(w2h + bo);
        bf8_t bl = *(const bf8_t*)(w2l + bo);
        acc = __builtin_amdgcn_mfma_f32_16x16x32_bf16(ah, bh, acc, 0, 0, 0);
        acc = __builtin_amdgcn_mfma_f32_16x16x32_bf16(ah, bl, acc, 0, 0, 0);
        acc = __builtin_amdgcn_mfma_f32_16x16x32_bf16(al, bh, acc, 0, 0, 0);
    }
    float4 dv4 = *(const float4*)(dinv + rb + quad * 4);
    float dvv[4] = {dv4.x, dv4.y, dv4.z, dv4.w};
#pragma unroll
    for (int r = 0; r < 4; ++r)
        h2[(size_t)(rb + quad * 4 + r) * DD + t * 16 + m] = f2h(dvv[r] * acc[r]);
}

// final aggregation over pre-scaled h2s: out[i] = relu(dinv_i*(Σ h2s[s] +
// h2s[i]) + b2)
__global__ __launch_bounds__(256) void k_agg(const ushort* __restrict__ h,
                                             const float* __restrict__ dinv,
                                             const int2* __restrict__ offs2,
                                             const ushort* __restrict__ csru,
                                             const float* __restrict__ bias,
                                             float* __restrict__ outf) {
    int wave = threadIdx.x >> 6;
    int lane = threadIdx.x & 63;
    int node = blockIdx.x * 4 + wave;   // grid = NN/4 exactly
    int q = lane >> 4;
    int l = lane & 15;
    int2 oe = offs2[node];
    int e1 = oe.y;
    float a[8] = {0.f, 0.f, 0.f, 0.f, 0.f, 0.f, 0.f, 0.f};
    for (int eb = oe.x; eb < e1; eb += 32) {
        int s[8];
#pragma unroll
        for (int j = 0; j < 8; ++j) {
            int e = eb + q + 4 * j;
            int er = (e < e1) ? e : (e1 - 1);
            er = (er < 0) ? 0 : er;
            int sv = (int)csru[er];
            s[j] = (e < e1) ? sv : ZROW;
        }
        us8 v[8];
#pragma unroll
        for (int j = 0; j < 8; ++j)
            v[j] = *(const us8*)(h + ((size_t)s[j] << 7) + 8 * l);
#pragma unroll
        for (int j = 0; j < 8; ++j) {
#pragma unroll
            for (int d = 0; d < 8; ++d) a[d] += h2f(v[j][d]);
        }
    }
    if (q == 0) {  // self-loop: + h2s[node]
        us8 v = *(const us8*)(h + ((size_t)node << 7) + 8 * l);
#pragma unroll
        for (int j = 0; j < 8; ++j) a[j] += h2f(v[j]);
    }
#pragma unroll
    for (int j = 0; j < 8; ++j) {
        a[j] += __shfl_xor(a[j], 16, 64);
        a[j] += __shfl_xor(a[j], 32, 64);
    }
    if (q == 0) {
        float dnode = dinv[node];
        float* op = outf + (size_t)node * DD + 8 * l;
        const float* bp = bias + 8 * l;
        float4 o0, o1;
        o0.x = fmaxf(dnode * a[0] + bp[0], 0.f);
        o0.y = fmaxf(dnode * a[1] + bp[1], 0.f);
        o0.z = fmaxf(dnode * a[2] + bp[2], 0.f);
        o0.w = fmaxf(dnode * a[3] + bp[3], 0.f);
        o1.x = fmaxf(dnode * a[4] + bp[4], 0.f);
        o1.y = fmaxf(dnode * a[5] + bp[5], 0.f);
        o1.z = fmaxf(dnode * a[6] + bp[6], 0.f);
        o1.w = fmaxf(dnode * a[7] + bp[7], 0.f);
        *(float4*)op = o0;
        *(float4*)(op + 4) = o1;
    }
}

extern "C" void kernel_launch(void* const* d_in, const int* in_sizes, int n_in,
                              void* d_out, int out_size, void* d_ws, size_t ws_size,
                              hipStream_t stream) {
    const float* x  = (const float*)d_in[0];
    const int*   ei = (const int*)d_in[1];
    const float* W1 = (const float*)d_in[2];
    const float* b1 = (const float*)d_in[3];
    const float* W2 = (const float*)d_in[4];
    const float* b2 = (const float*)d_in[5];
    float* out = (float*)d_out;

    const int* src = ei;        // edge_index[0]
    const int* dst = ei + NE;   // edge_index[1]

    int*          wsi  = (int*)d_ws;
    float*        wsf  = (float*)d_ws;
    ushort*       wsu  = (ushort*)d_ws;
    unsigned int* wsuw = (unsigned int*)d_ws;
    int*    lcnt_g = wsi + OF_LCNT;
    int*    lofs_g = wsi + OF_LOFS;
    float*  dinv   = wsf + OF_DINV;
    int*    deg    = wsi + OF_DEG;
    int2*   offs2  = (int2*)(wsi + OF_OFFS2);
    unsigned int* tmp2 = wsuw + OF_TMP2;
    ushort* csru   = wsu + (size_t)OF_CSRU * 2;
    ushort* h1     = wsu + (size_t)OF_H1 * 2;
    ushort* h2     = wsu + (size_t)OF_H2 * 2;
    ushort* w1h    = wsu + (size_t)OF_W1H * 2;
    ushort* w1l    = wsu + (size_t)OF_W1L * 2;
    ushort* w2h    = wsu + (size_t)OF_W2H * 2;
    ushort* w2l    = wsu + (size_t)OF_W2L * 2;

    // 0: zero deg + zero rows (kernel, not memset — graph-capture safe)
    hipLaunchKernelGGL(k_zero, dim3(196), dim3(256), 0, stream, deg, h1, h2);
    // 1: wconv (16 blk) || edge shuffle + deg histogram (196 blk)
    hipLaunchKernelGGL(k_ws, dim3(16 + 196), dim3(256), 0, stream,
                       W1, W2, w1h, w1l, w2h, w2l,
                       src, dst, lcnt_g, lofs_g, tmp2, deg);
    // 2: sort (196 blk) || layer-1 GEMM -> pre-scaled fp16 h1s (782 blk)
    hipLaunchKernelGGL(k_sg, dim3(196 + (NSTRIP + 3) / 4), dim3(256), 0, stream,
                       lcnt_g, lofs_g, tmp2, deg, csru, offs2, dinv,
                       x, w1h, w1l, h1);
    // 3: fused agg(L1)+relu+b1 -> @W2 -> pre-scaled fp16 h2s
    hipLaunchKernelGGL(k_aggmm, dim3(NSTRIP), dim3(512), 0, stream,
                       h1, dinv, offs2, csru, b1, w2h, w2l, h2);
    // 4: final aggregation -> out
    hipLaunchKernelGGL(k_agg, dim3(NN / 4), dim3(256), 0, stream,
                       h2, dinv, offs2, csru, b2, out);
}